// Round 1
// baseline (326.734 us; speedup 1.0000x reference)
//
#include <hip/hip_runtime.h>

// Problem constants (B=1024, A=256, E=4, M1=128, M2=16, H1=32, H2=64)
#define A_SZ   256
#define XROW   1537          // 6*A + 1 floats per x row
#define NTHR   256

// Per-thread MLP + g-streaming + wave-local P partial accumulation.
// 'e' may be an SGPR (uniform wave -> scalar weight loads) or per-lane VGPR
// (mixed boundary wave -> vector loads). Same source, inlined twice.
__device__ __forceinline__ void process_tile(
    int e, float v, int w, int lane,
    const float* __restrict__ W1, const float* __restrict__ b1,
    const float* __restrict__ W2, const float* __restrict__ b2,
    const float* __restrict__ W3, const float* __restrict__ b3,
    float (*g_l)[8][68],          // [wave][m_local][i' padded]
    const float (*Rm_l)[264],     // [c][i global, mask-folded]
    float (*Pw_l)[128][4])        // [wave][m][c] partials
{
    // ---- h2 = relu(W2^T relu(v*W1 + b1) + b2), h2 in registers ----
    float h2[64];
    const float* b2e = b2 + e * 64;
    #pragma unroll
    for (int o = 0; o < 64; ++o) h2[o] = b2e[o];

    const float* W1e = W1 + e * 32;
    const float* b1e = b1 + e * 32;
    const float* W2e = W2 + e * 2048;
    for (int i = 0; i < 32; ++i) {            // i dynamic; h1_i recomputed (no array)
        float h1i = fmaxf(fmaf(v, W1e[i], b1e[i]), 0.f);
        const float* w2row = W2e + i * 64;
        #pragma unroll
        for (int o = 0; o < 64; ++o) h2[o] = fmaf(h1i, w2row[o], h2[o]);
    }
    #pragma unroll
    for (int o = 0; o < 64; ++o) h2[o] = fmaxf(h2[o], 0.f);

    // ---- stream g in chunks of 8 m's; wave-local transposed P phase ----
    const float* W3e = W3 + e * 8192;
    const float* b3e = b3 + e * 128;
    const int m_loc = lane >> 3;
    const int c     = (lane >> 1) & 3;
    const int half  = lane & 1;

    for (int mb = 0; mb < 16; ++mb) {
        float g8[8];
        #pragma unroll
        for (int j = 0; j < 8; ++j) g8[j] = b3e[mb * 8 + j];
        #pragma unroll
        for (int i = 0; i < 64; ++i) {        // full unroll: h2[i] stays in regs
            const float* w3row = W3e + i * 128 + mb * 8;
            float h = h2[i];
            #pragma unroll
            for (int j = 0; j < 8; ++j) g8[j] = fmaf(h, w3row[j], g8[j]);
        }
        #pragma unroll
        for (int j = 0; j < 8; ++j) g_l[w][j][lane] = g8[j];
        // wave-lockstep: ensure all lanes' ds_writes landed before ds_reads
        asm volatile("s_waitcnt lgkmcnt(0)" ::: "memory");

        float acc = 0.f;
        #pragma unroll
        for (int k = 0; k < 8; ++k) {
            const float4 gv = *(const float4*)&g_l[w][m_loc][half * 32 + 4 * k];
            const float4 rv = *(const float4*)&Rm_l[c][(w << 6) + half * 32 + 4 * k];
            acc = fmaf(gv.x, rv.x, acc);
            acc = fmaf(gv.y, rv.y, acc);
            acc = fmaf(gv.z, rv.z, acc);
            acc = fmaf(gv.w, rv.w, acc);
        }
        acc += __shfl_xor(acc, 1);            // combine the two halves
        if (half == 0) Pw_l[w][mb * 8 + m_loc][c] = acc;  // unique writer, no atomic
        // anti-dep: reads of this chunk complete before next chunk's writes
        asm volatile("s_waitcnt lgkmcnt(0)" ::: "memory");
    }
}

__global__ void __launch_bounds__(NTHR)
be_kernel(const float* __restrict__ x,
          const float* __restrict__ W1, const float* __restrict__ b1,
          const float* __restrict__ W2, const float* __restrict__ b2,
          const float* __restrict__ W3, const float* __restrict__ b3,
          float* __restrict__ out)
{
    __shared__ float vca[256];          // compacted v
    __shared__ int   eca[256];          // compacted expert
    __shared__ float Rm_l[4][264];      // R^T, mask folded, padded
    __shared__ float g_l[4][8][68];     // per-wave g chunk, padded
    __shared__ float Pw_l[4][128][4];   // per-wave P partials
    __shared__ int   cntw[4][4];        // [wave][expert] counts

    const int tid  = threadIdx.x;
    const int b    = blockIdx.x;
    const int lane = tid & 63;
    const int w    = tid >> 6;
    const long xb  = (long)b * XROW;

    // ---- load this thread's (a = tid) element ----
    float v  = x[xb + 2 * tid];
    float tf = x[xb + 2 * tid + 1];
    int e = (int)tf;                       // trunc toward zero == jnp astype
    e = max(0, min(3, e));
    int N = (int)x[xb + 1536];
    float maskf = (tid < N) ? 1.f : 0.f;

    // ---- deterministic expert compaction via ballots ----
    unsigned long long mybal = 0ull;
    #pragma unroll
    for (int q = 0; q < 4; ++q) {
        unsigned long long bq = __ballot(e == q);
        if (lane == 0) cntw[w][q] = __popcll(bq);
        if (e == q) mybal = bq;
    }
    int rank = __popcll(mybal & ((1ull << lane) - 1ull));
    __syncthreads();

    int off = 0;
    #pragma unroll
    for (int q = 0; q < 4; ++q) {
        #pragma unroll
        for (int w2 = 0; w2 < 4; ++w2) {
            int cw = cntw[w2][q];
            if (q < e || (q == e && w2 < w)) off += cw;
        }
    }
    const int ci = off + rank;             // my compact slot in [0,256)
    vca[ci] = v;
    eca[ci] = e;
    #pragma unroll
    for (int c = 0; c < 4; ++c)
        Rm_l[c][ci] = x[xb + 512 + 4 * tid + c] * maskf;
    __syncthreads();

    // ---- process compact slot 'tid' ----
    float v2 = vca[tid];
    int   e2 = eca[tid];
    int   ef = __builtin_amdgcn_readfirstlane(e2);
    if (__ballot(e2 != ef) == 0ull) {
        // wave-uniform expert: scalar (SGPR) weight loads
        process_tile(ef, v2, w, lane, W1, b1, W2, b2, W3, b3, g_l, Rm_l, Pw_l);
    } else {
        // mixed boundary wave: per-lane weight loads
        process_tile(e2, v2, w, lane, W1, b1, W2, b2, W3, b3, g_l, Rm_l, Pw_l);
    }
    __syncthreads();

    // ---- reduce P over waves (deterministic order), stash in g_l space ----
    float* Pr = &g_l[0][0][0];             // 512 floats needed, 2176 available
    const float* Pf = &Pw_l[0][0][0];
    #pragma unroll
    for (int r = 0; r < 2; ++r) {
        int idx = r * 256 + tid;
        Pr[idx] = ((Pf[idx] + Pf[512 + idx]) + (Pf[1024 + idx] + Pf[1536 + idx]));
    }
    __syncthreads();

    // ---- D[m][n] = sum_c P[m][c] * P[n][c]  (Q == P[:16,:]^T) ----
    float* outb = out + (long)b * 2048;
    #pragma unroll
    for (int r = 0; r < 8; ++r) {
        int o = r * 256 + tid;
        int m = o >> 4, n = o & 15;
        float d = 0.f;
        #pragma unroll
        for (int c = 0; c < 4; ++c)
            d = fmaf(Pr[m * 4 + c], Pr[n * 4 + c], d);
        outb[o] = d;
    }
}

extern "C" void kernel_launch(void* const* d_in, const int* in_sizes, int n_in,
                              void* d_out, int out_size, void* d_ws, size_t ws_size,
                              hipStream_t stream)
{
    const float* x  = (const float*)d_in[0];
    const float* W1 = (const float*)d_in[1];
    const float* b1 = (const float*)d_in[2];
    const float* W2 = (const float*)d_in[3];
    const float* b2 = (const float*)d_in[4];
    const float* W3 = (const float*)d_in[5];
    const float* b3 = (const float*)d_in[6];
    float* out = (float*)d_out;

    be_kernel<<<1024, NTHR, 0, stream>>>(x, W1, b1, W2, b2, W3, b3, out);
}